// Round 1
// baseline (479.403 us; speedup 1.0000x reference)
//
#include <hip/hip_runtime.h>

// ---------------------------------------------------------------------------
// EagerAttention: x[B,T,D] -> QKV proj -> RoPE -> causal GQA attention -> out proj
// B=2 T=2048 D=2048 NH=16 NKV=4 HD=128, fp32 in/out, bf16 MFMA internally.
// ---------------------------------------------------------------------------

#define T_SZ 2048
#define D_SZ 2048
#define BT   4096   // B*T

typedef __attribute__((ext_vector_type(8))) short bf16x8;
typedef __attribute__((ext_vector_type(4))) float f32x4;

__device__ __forceinline__ unsigned short f2b(float f) {
  unsigned u = __float_as_uint(f);
  u = (u + 0x7fffu + ((u >> 16) & 1u)) >> 16;   // RNE
  return (unsigned short)u;
}
__device__ __forceinline__ float b2f(unsigned short h) {
  return __uint_as_float(((unsigned)h) << 16);
}

union Pack8 { unsigned short us[8]; uint4 v; };

// --------------------------- elementwise cast ------------------------------
__global__ __launch_bounds__(256) void cast_f32_bf16(
    const float* __restrict__ in, unsigned short* __restrict__ out) {
  int i = (blockIdx.x * 256 + threadIdx.x) * 4;
  float4 v = *(const float4*)(in + i);
  ushort4 o;
  o.x = f2b(v.x); o.y = f2b(v.y); o.z = f2b(v.z); o.w = f2b(v.w);
  *(ushort4*)(out + i) = o;
}

// ---------------- cast + transpose: W[K,N] f32 -> WT[N,K] bf16 -------------
__global__ __launch_bounds__(256) void cast_transpose(
    const float* __restrict__ W, unsigned short* __restrict__ WT, int K, int N) {
  __shared__ float tile[64][68];
  int n0 = blockIdx.x * 64, k0 = blockIdx.y * 64;
  int t = threadIdx.x;
#pragma unroll
  for (int i = 0; i < 4; i++) {
    int c = t + 256 * i;              // 1024 chunks: 64 rows x 16 col-chunks(4)
    int r = c >> 4, cc = c & 15;
    float4 v = *(const float4*)(W + (size_t)(k0 + r) * N + n0 + cc * 4);
    tile[r][cc * 4 + 0] = v.x; tile[r][cc * 4 + 1] = v.y;
    tile[r][cc * 4 + 2] = v.z; tile[r][cc * 4 + 3] = v.w;
  }
  __syncthreads();
#pragma unroll
  for (int i = 0; i < 2; i++) {
    int c = t + 256 * i;              // 512 chunks: 64 n x 8 k-chunks(8)
    int n = c >> 3, kc = c & 7;
    Pack8 p;
#pragma unroll
    for (int j = 0; j < 8; j++) p.us[j] = f2b(tile[kc * 8 + j][n]);
    *(uint4*)(WT + (size_t)(n0 + n) * K + k0 + kc * 8) = p.v;
  }
}

// ------------------- GEMM: C[M,N] = A[M,K] @ Bt[N,K]^T ---------------------
// m93 structure: 128x128 tile, BK=32, 4 waves, 4x4 16x16 MFMA tiles per wave.
template <int OUT_BF16>
__global__ __launch_bounds__(256) void gemm_bt(
    const unsigned short* __restrict__ A, const unsigned short* __restrict__ Bt,
    void* __restrict__ C, int M, int N, int K) {
  __shared__ unsigned short As[128 * 32];
  __shared__ unsigned short Bs[128 * 32];
  int t = threadIdx.x;
  int lane = t & 63, wave = t >> 6;
  int m0 = blockIdx.y * 128, n0 = blockIdx.x * 128;
  int wm = (wave >> 1) * 64, wn = (wave & 1) * 64;
  int fr = lane & 15, fq = lane >> 4;
  f32x4 acc[4][4];
#pragma unroll
  for (int mi = 0; mi < 4; mi++)
#pragma unroll
    for (int ni = 0; ni < 4; ni++) acc[mi][ni] = (f32x4){0.f, 0.f, 0.f, 0.f};

  for (int k0 = 0; k0 < K; k0 += 32) {
    __syncthreads();
#pragma unroll
    for (int i = 0; i < 2; i++) {
      int c = t + 256 * i;            // 512 chunks: 128 rows x 4 chunks(8)
      int r = c >> 2, cc = c & 3;
      *(uint4*)(As + r * 32 + cc * 8) =
          *(const uint4*)(A + (size_t)(m0 + r) * K + k0 + cc * 8);
      *(uint4*)(Bs + r * 32 + cc * 8) =
          *(const uint4*)(Bt + (size_t)(n0 + r) * K + k0 + cc * 8);
    }
    __syncthreads();
    bf16x8 a[4], b[4];
#pragma unroll
    for (int mi = 0; mi < 4; mi++)
      a[mi] = *(const bf16x8*)(As + (wm + 16 * mi + fr) * 32 + fq * 8);
#pragma unroll
    for (int ni = 0; ni < 4; ni++)
      b[ni] = *(const bf16x8*)(Bs + (wn + 16 * ni + fr) * 32 + fq * 8);
#pragma unroll
    for (int mi = 0; mi < 4; mi++)
#pragma unroll
      for (int ni = 0; ni < 4; ni++)
        acc[mi][ni] = __builtin_amdgcn_mfma_f32_16x16x32_bf16(
            a[mi], b[ni], acc[mi][ni], 0, 0, 0);
  }
#pragma unroll
  for (int mi = 0; mi < 4; mi++)
#pragma unroll
    for (int ni = 0; ni < 4; ni++)
#pragma unroll
      for (int r = 0; r < 4; r++) {
        int row = m0 + wm + 16 * mi + fq * 4 + r;
        int col = n0 + wn + 16 * ni + fr;
        float v = acc[mi][ni][r];
        if (OUT_BF16)
          ((unsigned short*)C)[(size_t)row * N + col] = f2b(v);
        else
          ((float*)C)[(size_t)row * N + col] = v;
      }
}

// ------------------------------ RoPE (in-place) ----------------------------
// X rows are [b*T + t], row length STRIDE; head h occupies cols h*128..+128.
// Thread owns pair (d, d+64), d in [0,64).
template <int LOGH, int STRIDE>
__global__ __launch_bounds__(256) void rope_inplace(unsigned short* __restrict__ X) {
  int p = blockIdx.x * 256 + threadIdx.x;
  int d = p & 63;
  int h = (p >> 6) & ((1 << LOGH) - 1);
  int row = p >> (6 + LOGH);
  int tpos = row & (T_SZ - 1);
  size_t base = (size_t)row * STRIDE + h * 128 + d;
  float u1 = b2f(X[base]), u2 = b2f(X[base + 64]);
  // inv_freq = theta^(-d/64); ln(1e6)/64 = 0.21586735246819178
  float inv = expf(-(float)d * 0.21586735246819178f);
  float ang = (float)tpos * inv;
  float c = cosf(ang), s = sinf(ang);
  X[base]      = f2b(u1 * c - u2 * s);
  X[base + 64] = f2b(u2 * c + u1 * s);
}

// --------- V transpose: KVb[.,512 + kvh*128 + n] -> VT[b,kvh,n,t] ----------
__global__ __launch_bounds__(256) void transpose_v(
    const unsigned short* __restrict__ V /* KVb + 512, row stride 1024 */,
    unsigned short* __restrict__ VT) {
  __shared__ unsigned short tile[64][72];
  int t0 = blockIdx.x * 64;
  int n0 = blockIdx.y * 64;        // within 128
  int bk = blockIdx.z;             // b*4 + kvh
  int b = bk >> 2, kvh = bk & 3;
  int t = threadIdx.x;
#pragma unroll
  for (int i = 0; i < 2; i++) {
    int c = t + 256 * i;           // 512 chunks: 64 t-rows x 8 n-chunks(8)
    int r = c >> 3, cc = c & 7;
    *(uint4*)&tile[r][cc * 8] = *(const uint4*)(
        V + (size_t)(b * T_SZ + t0 + r) * 1024 + kvh * 128 + n0 + cc * 8);
  }
  __syncthreads();
#pragma unroll
  for (int i = 0; i < 2; i++) {
    int c = t + 256 * i;           // 512 chunks: 64 n-rows x 8 t-chunks(8)
    int n = c >> 3, tc = c & 7;
    Pack8 p;
#pragma unroll
    for (int j = 0; j < 8; j++) p.us[j] = tile[tc * 8 + j][n];
    *(uint4*)(VT + ((size_t)bk * 128 + n0 + n) * T_SZ + t0 + tc * 8) = p.v;
  }
}

// -------------------------- flash attention --------------------------------
// grid (qt=32, h=16, b=2), 256 threads. 64-row Q tile; wave w owns rows
// w*16..+15. K/V tiles of 64. Online softmax; S and PV both on MFMA.
__global__ __launch_bounds__(256) void attn(
    const unsigned short* __restrict__ Q,   // [BT, 2048]
    const unsigned short* __restrict__ KV,  // [BT, 1024], K in cols 0..511
    const unsigned short* __restrict__ VT,  // [B,4,128,T]
    unsigned short* __restrict__ O) {       // [BT, 2048]
  __shared__ unsigned short Qs[64 * 136];   // +8 pad: stride 272B (17x16B)
  __shared__ unsigned short Ks[64 * 136];
  __shared__ unsigned short Vt[128 * 72];   // [hd][kv], +8 pad
  __shared__ unsigned short Ps[4][16 * 72]; // per-wave P round-trip
  int qt = blockIdx.x, h = blockIdx.y, b = blockIdx.z;
  int kvh = h >> 2;
  int t = threadIdx.x, lane = t & 63, w = t >> 6;
  int fr = lane & 15, fq = lane >> 4;

  // stage Q tile
#pragma unroll
  for (int i = 0; i < 4; i++) {
    int c = t + 256 * i;           // 1024 chunks: 64 rows x 16 chunks(8)
    int r = c >> 4, cc = c & 15;
    *(uint4*)(Qs + r * 136 + cc * 8) = *(const uint4*)(
        Q + (size_t)(b * T_SZ + qt * 64 + r) * 2048 + h * 128 + cc * 8);
  }
  __syncthreads();
  bf16x8 qf[4];
#pragma unroll
  for (int kk = 0; kk < 4; kk++)
    qf[kk] = *(const bf16x8*)(Qs + (w * 16 + fr) * 136 + kk * 32 + fq * 8);

  f32x4 o[8];
#pragma unroll
  for (int i = 0; i < 8; i++) o[i] = (f32x4){0.f, 0.f, 0.f, 0.f};
  float mrow[4] = {-1e30f, -1e30f, -1e30f, -1e30f};
  float lrow[4] = {0.f, 0.f, 0.f, 0.f};
  const float scale = 0.08838834764831845f;  // 128^-0.5

  for (int kt = 0; kt <= qt; kt++) {
    __syncthreads();
    // stage K tile [64 kv-rows][128 hd]
#pragma unroll
    for (int i = 0; i < 4; i++) {
      int c = t + 256 * i;
      int r = c >> 4, cc = c & 15;
      *(uint4*)(Ks + r * 136 + cc * 8) = *(const uint4*)(
          KV + (size_t)(b * T_SZ + kt * 64 + r) * 1024 + kvh * 128 + cc * 8);
    }
    // stage V tile transposed [128 hd][64 kv]
#pragma unroll
    for (int i = 0; i < 4; i++) {
      int c = t + 256 * i;         // 1024 chunks: 128 n-rows x 8 chunks(8)
      int n = c >> 3, cc = c & 7;
      *(uint4*)(Vt + n * 72 + cc * 8) = *(const uint4*)(
          VT + ((size_t)(b * 4 + kvh) * 128 + n) * T_SZ + kt * 64 + cc * 8);
    }
    __syncthreads();

    // S = Q K^T  (M=16 q-rows, N=64 kv-cols, K=128)
    f32x4 s[4];
#pragma unroll
    for (int nn = 0; nn < 4; nn++) {
      s[nn] = (f32x4){0.f, 0.f, 0.f, 0.f};
#pragma unroll
      for (int kk = 0; kk < 4; kk++) {
        bf16x8 kf = *(const bf16x8*)(Ks + (nn * 16 + fr) * 136 + kk * 32 + fq * 8);
        s[nn] = __builtin_amdgcn_mfma_f32_16x16x32_bf16(qf[kk], kf, s[nn], 0, 0, 0);
      }
    }
    int rowg = qt * 64 + w * 16 + fq * 4;   // + r
    if (kt == qt) {
#pragma unroll
      for (int nn = 0; nn < 4; nn++)
#pragma unroll
        for (int r = 0; r < 4; r++) {
          int colg = kt * 64 + nn * 16 + fr;
          float v = s[nn][r] * scale;
          s[nn][r] = (colg <= rowg + r) ? v : -1e30f;
        }
    } else {
#pragma unroll
      for (int nn = 0; nn < 4; nn++)
#pragma unroll
        for (int r = 0; r < 4; r++) s[nn][r] *= scale;
    }
    // online softmax update (rows live in 16-lane quads; reduce with shfl_xor)
#pragma unroll
    for (int r = 0; r < 4; r++) {
      float mx = fmaxf(fmaxf(s[0][r], s[1][r]), fmaxf(s[2][r], s[3][r]));
#pragma unroll
      for (int off = 1; off < 16; off <<= 1) mx = fmaxf(mx, __shfl_xor(mx, off, 64));
      float mnew = fmaxf(mrow[r], mx);
      float sum = 0.f;
#pragma unroll
      for (int nn = 0; nn < 4; nn++) {
        float p = __expf(s[nn][r] - mnew);
        sum += p;
        Ps[w][(fq * 4 + r) * 72 + nn * 16 + fr] = f2b(p);
      }
#pragma unroll
      for (int off = 1; off < 16; off <<= 1) sum += __shfl_xor(sum, off, 64);
      float alpha = __expf(mrow[r] - mnew);
      lrow[r] = lrow[r] * alpha + sum;
      mrow[r] = mnew;
#pragma unroll
      for (int nt = 0; nt < 8; nt++) o[nt][r] *= alpha;
    }
    __syncthreads();   // Ps visibility before A-layout re-read
    // O += P V   (M=16, N=128, K=64)
#pragma unroll
    for (int kk = 0; kk < 2; kk++) {
      bf16x8 pf = *(const bf16x8*)(Ps[w] + fr * 72 + kk * 32 + fq * 8);
#pragma unroll
      for (int nt = 0; nt < 8; nt++) {
        bf16x8 vf = *(const bf16x8*)(Vt + (nt * 16 + fr) * 72 + kk * 32 + fq * 8);
        o[nt] = __builtin_amdgcn_mfma_f32_16x16x32_bf16(pf, vf, o[nt], 0, 0, 0);
      }
    }
  }
  // epilogue: O / l  -> bf16 [BT, 2048]
#pragma unroll
  for (int nt = 0; nt < 8; nt++)
#pragma unroll
    for (int r = 0; r < 4; r++) {
      int rowg = b * T_SZ + qt * 64 + w * 16 + fq * 4 + r;
      int col = h * 128 + nt * 16 + fr;
      O[(size_t)rowg * 2048 + col] = f2b(o[nt][r] / lrow[r]);
    }
}

// ---------------------------------------------------------------------------
extern "C" void kernel_launch(void* const* d_in, const int* in_sizes, int n_in,
                              void* d_out, int out_size, void* d_ws, size_t ws_size,
                              hipStream_t stream) {
  const float* x  = (const float*)d_in[0];
  const float* wq = (const float*)d_in[1];
  const float* wk = (const float*)d_in[2];
  const float* wv = (const float*)d_in[3];
  const float* wo = (const float*)d_in[4];
  float* out = (float*)d_out;

  unsigned short* xb  = (unsigned short*)d_ws;            // [4096,2048]
  unsigned short* wqT = xb  + (size_t)4096 * 2048;        // [2048,2048]
  unsigned short* wkT = wqT + (size_t)2048 * 2048;        // [512,2048]
  unsigned short* wvT = wkT + (size_t)512 * 2048;         // [512,2048] (adjacent: merged KV GEMM)
  unsigned short* woT = wvT + (size_t)512 * 2048;         // [2048,2048]
  unsigned short* Qb  = woT + (size_t)2048 * 2048;        // [4096,2048]
  unsigned short* KVb = Qb  + (size_t)4096 * 2048;        // [4096,1024]: K | V
  unsigned short* VTb = KVb + (size_t)4096 * 1024;        // [2,4,128,2048]
  unsigned short* AOb = VTb + (size_t)4096 * 512;         // [4096,2048]
  // total: ~84 MB of ws

  cast_f32_bf16<<<8192, 256, 0, stream>>>(x, xb);
  cast_transpose<<<dim3(32, 32), 256, 0, stream>>>(wq, wqT, 2048, 2048);
  cast_transpose<<<dim3(8, 32),  256, 0, stream>>>(wk, wkT, 2048, 512);
  cast_transpose<<<dim3(8, 32),  256, 0, stream>>>(wv, wvT, 2048, 512);
  cast_transpose<<<dim3(32, 32), 256, 0, stream>>>(wo, woT, 2048, 2048);

  gemm_bt<1><<<dim3(16, 32), 256, 0, stream>>>(xb, wqT, Qb,  4096, 2048, 2048);
  gemm_bt<1><<<dim3(8, 32),  256, 0, stream>>>(xb, wkT, KVb, 4096, 1024, 2048); // K|V merged

  rope_inplace<4, 2048><<<16384, 256, 0, stream>>>(Qb);
  rope_inplace<2, 1024><<<4096,  256, 0, stream>>>(KVb);
  transpose_v<<<dim3(32, 2, 8), 256, 0, stream>>>(KVb + 512, VTb);

  attn<<<dim3(32, 16, 2), 256, 0, stream>>>(Qb, KVb, VTb, AOb);

  gemm_bt<0><<<dim3(16, 32), 256, 0, stream>>>(AOb, woT, (void*)out, 4096, 2048, 2048);
}